// Round 1
// baseline (104.596 us; speedup 1.0000x reference)
//
#include <hip/hip_runtime.h>

// ConvLSTMSNN: the SConv2dLSTM stack can never spike (mem = sigmoid*tanh is
// strictly inside (-1,1), pool(mem) - THRESH(=1) < 0 always), so spk1/2/3 == 0
// for all t. The output therefore only depends on the FC-path recurrences
// driven by the biases fb1/fb2 (batch-independent):
//   cur      = fb1                         (constant over t and batch)
//   mem4[j]  = 0.9*mem4[j] + fb1[j] - (mem4[j] > 1)       [reset from PRIOR mem]
//   spk4[j]  = (mem4[j] - 1 > 0)
//   cur2[k]  = sum_j spk4[j]*fw2[k][j] + fb2[k]
//   mem5[k]  = 0.9*mem5[k] + cur2[k] - (mem5[k] > 1)
//   spk5[k]  = (mem5[k] - 1 > 0)
// Output: spk_rec [T,B,2] then mem_rec [T,B,2], each row broadcast over B.

#define T_STEPS 100
#define BATCH 64
#define NF 128   // FC1 features
#define NO 2     // FC2 features

__global__ void __launch_bounds__(128)
snn_fc_only_kernel(const float* __restrict__ fb1,   // [128]
                   const float* __restrict__ fw2,   // [2,128]
                   const float* __restrict__ fb2,   // [2]
                   float* __restrict__ out)         // [2*T*B*2]
{
    __shared__ float spk4[T_STEPS][NF];      // 51200 B
    __shared__ float cur2[T_STEPS][NO];      //   800 B
    __shared__ float res_spk[T_STEPS][NO];   //   800 B
    __shared__ float res_mem[T_STEPS][NO];   //   800 B

    const int j = threadIdx.x;  // 0..127

    // ---- step 1: per-feature mem4 recurrence (Leaky, reset_mechanism='subtract')
    {
        float mem4 = 0.0f;
        const float cur = fb1[j];
        #pragma unroll 4
        for (int t = 0; t < T_STEPS; ++t) {
            const float reset = (mem4 > 1.0f) ? 1.0f : 0.0f;  // from PRIOR mem, detached
            mem4 = 0.9f * mem4 + cur - reset * 1.0f;
            spk4[t][j] = ((mem4 - 1.0f) > 0.0f) ? 1.0f : 0.0f;
        }
    }
    __syncthreads();

    // ---- step 2: cur2[t][k] = fb2[k] + sum_j spk4[t][j] * fw2[k][j]
    for (int idx = j; idx < T_STEPS * NO; idx += 128) {
        const int t = idx >> 1;
        const int k = idx & 1;
        float s = fb2[k];
        const float* wrow = fw2 + k * NF;
        #pragma unroll 8
        for (int jj = 0; jj < NF; ++jj) s += spk4[t][jj] * wrow[jj];
        cur2[t][k] = s;
    }
    __syncthreads();

    // ---- step 3: mem5 recurrence (2 features, sequential over t)
    if (j < NO) {
        float mem5 = 0.0f;
        for (int t = 0; t < T_STEPS; ++t) {
            const float reset = (mem5 > 1.0f) ? 1.0f : 0.0f;
            mem5 = 0.9f * mem5 + cur2[t][j] - reset * 1.0f;
            res_spk[t][j] = ((mem5 - 1.0f) > 0.0f) ? 1.0f : 0.0f;
            res_mem[t][j] = mem5;
        }
    }
    __syncthreads();

    // ---- step 4: broadcast over batch.
    // spk_rec at out[t*B*2 + b*2 + k], mem_rec at out[T*B*2 + ...]
    const int total = T_STEPS * BATCH * NO;  // 12800
    for (int idx = j; idx < total; idx += 128) {
        const int t = idx / (BATCH * NO);
        const int k = idx & 1;
        out[idx]         = res_spk[t][k];
        out[total + idx] = res_mem[t][k];
    }
}

extern "C" void kernel_launch(void* const* d_in, const int* in_sizes, int n_in,
                              void* d_out, int out_size, void* d_ws, size_t ws_size,
                              hipStream_t stream) {
    // setup_inputs order: x, w1, b1, w2, b2, w3, b3, fw1, fb1, fw2, fb2
    const float* fb1 = (const float*)d_in[8];
    const float* fw2 = (const float*)d_in[9];
    const float* fb2 = (const float*)d_in[10];
    float* out = (float*)d_out;

    snn_fc_only_kernel<<<1, 128, 0, stream>>>(fb1, fw2, fb2, out);
}

// Round 2
// 98.423 us; speedup vs baseline: 1.0627x; 1.0627x over previous
//
#include <hip/hip_runtime.h>

// ConvLSTMSNN: the SConv2dLSTM stack can never spike:
//   mem = sigmoid(o)*tanh(syn)  =>  |mem| < 1 strictly,
//   pool2(mem) < 1  =>  spike_ste(pool(mem) - 1.0) == 0  always.
// So spk1/spk2/spk3 == 0 for all t, and the output depends only on the
// FC-path recurrences driven by biases fb1/fb2 (batch-independent):
//   cur     = fb1                          (constant over t and batch)
//   mem4[j] = 0.9*mem4[j] + fb1[j] - (mem4[j] > 1)   [reset from PRIOR mem]
//   spk4[j] = (mem4[j] - 1 > 0)
//   cur2[k] = sum_j spk4[j]*fw2[k][j] + fb2[k]
//   mem5[k] = 0.9*mem5[k] + cur2[k] - (mem5[k] > 1)
//   spk5[k] = (mem5[k] - 1 > 0)
// Output: spk_rec [T,B,2] then mem_rec [T,B,2], each [T,2] row broadcast over B.
//
// R1: single block took ~15-20us (serial dots + 204KB of stores from one CU).
// R2: 64 blocks redundantly compute the tiny recurrence (deterministic,
// block-local => redundancy is free parallelism), each writes 1/64 of the
// broadcast output with float2 stores.

#define T_STEPS 100
#define BATCH 64
#define NF 128   // FC1 features
#define NO 2     // FC2 features
#define NBLK 64

__global__ void __launch_bounds__(128)
snn_fc_only_kernel(const float* __restrict__ fb1,   // [128]
                   const float* __restrict__ fw2,   // [2,128]
                   const float* __restrict__ fb2,   // [2]
                   float* __restrict__ out)         // [2*T*B*2] = 25600 floats
{
    __shared__ float  spk4[T_STEPS][NF];   // 51200 B
    __shared__ float  cur2[T_STEPS][NO];   //   800 B
    __shared__ float2 res_spk[T_STEPS];    //   800 B
    __shared__ float2 res_mem[T_STEPS];    //   800 B

    const int j = threadIdx.x;  // 0..127

    // ---- step 1: per-feature mem4 recurrence (Leaky, reset='subtract')
    {
        float mem4 = 0.0f;
        const float cur = fb1[j];
        #pragma unroll 4
        for (int t = 0; t < T_STEPS; ++t) {
            const float reset = (mem4 > 1.0f) ? 1.0f : 0.0f;  // prior mem, detached
            mem4 = 0.9f * mem4 + cur - reset;
            spk4[t][j] = ((mem4 - 1.0f) > 0.0f) ? 1.0f : 0.0f;
        }
    }
    __syncthreads();

    // ---- step 2: cur2[t][k] = fb2[k] + sum_j spk4[t][j]*fw2[k][j]
    // 200 (t,k) pairs over 128 threads; float4 LDS reads (spk4 row is
    // 128 contiguous floats, 16B-aligned).
    for (int idx = j; idx < T_STEPS * NO; idx += 128) {
        const int t = idx >> 1;
        const int k = idx & 1;
        float s = fb2[k];
        const float4* sp = (const float4*)spk4[t];
        const float4* wr = (const float4*)(fw2 + k * NF);
        #pragma unroll 8
        for (int jj = 0; jj < NF / 4; ++jj) {
            const float4 a = sp[jj];
            const float4 w = wr[jj];
            s += a.x * w.x + a.y * w.y + a.z * w.z + a.w * w.w;
        }
        cur2[t][k] = s;
    }
    __syncthreads();

    // ---- step 3: mem5 recurrence (2 features, sequential over t)
    if (j < NO) {
        float mem5 = 0.0f;
        for (int t = 0; t < T_STEPS; ++t) {
            const float reset = (mem5 > 1.0f) ? 1.0f : 0.0f;
            mem5 = 0.9f * mem5 + cur2[t][j] - reset;
            ((float*)&res_spk[t])[j] = ((mem5 - 1.0f) > 0.0f) ? 1.0f : 0.0f;
            ((float*)&res_mem[t])[j] = mem5;
        }
    }
    __syncthreads();

    // ---- step 4: broadcast over batch, split across blocks, float2 stores.
    // out[t*B*2 + b*2 + k]: per t the pattern (s0,s1) repeats B times.
    // spk half: 6400 float2; mem half: 6400 float2 at +12800 floats.
    float2* __restrict__ o_spk = (float2*)out;
    float2* __restrict__ o_mem = (float2*)(out + T_STEPS * BATCH * NO);
    const int stride = NBLK * 128;
    for (int i = blockIdx.x * 128 + j; i < T_STEPS * BATCH; i += stride) {
        const int t = i >> 6;  // i / BATCH
        o_spk[i] = res_spk[t];
        o_mem[i] = res_mem[t];
    }
}

extern "C" void kernel_launch(void* const* d_in, const int* in_sizes, int n_in,
                              void* d_out, int out_size, void* d_ws, size_t ws_size,
                              hipStream_t stream) {
    // setup_inputs order: x, w1, b1, w2, b2, w3, b3, fw1, fb1, fw2, fb2
    const float* fb1 = (const float*)d_in[8];
    const float* fw2 = (const float*)d_in[9];
    const float* fb2 = (const float*)d_in[10];
    float* out = (float*)d_out;

    snn_fc_only_kernel<<<NBLK, 128, 0, stream>>>(fb1, fw2, fb2, out);
}